// Round 6
// baseline (181.972 us; speedup 1.0000x reference)
//
#include <hip/hip_runtime.h>
#include <hip/hip_bf16.h>

typedef __bf16 bf16_t;
typedef __bf16 bf16x8 __attribute__((ext_vector_type(8)));
typedef __bf16 bf16x4 __attribute__((ext_vector_type(4)));
typedef float  f32x4  __attribute__((ext_vector_type(4)));

#define LN_EPS 1e-5f

// B=8, T=512, C=768 -> M = 4096, 4C = 3072

// ---------------- async global->LDS helper (16B per lane, wave-uniform LDS base) ----
typedef __attribute__((address_space(1))) void gvoid_t;
typedef __attribute__((address_space(3))) void lvoid_t;
__device__ __forceinline__ void glds16(const void* g, void* l) {
    __builtin_amdgcn_global_load_lds((gvoid_t*)g, (lvoid_t*)l, 16, 0, 0);
}

// ---------------- fp32 -> bf16 conversion ----------------
__global__ __launch_bounds__(256) void k_cvt4(const float* __restrict__ s0,
                                              const float* __restrict__ s1,
                                              const float* __restrict__ s2,
                                              const float* __restrict__ s3,
                                              bf16_t* __restrict__ dst, int n4) {
    const float* s = (blockIdx.y == 0) ? s0 : (blockIdx.y == 1) ? s1 : (blockIdx.y == 2) ? s2 : s3;
    bf16_t* d = dst + (size_t)blockIdx.y * ((size_t)n4 * 4);
    int i = blockIdx.x * 256 + threadIdx.x;
    if (i < n4) {
        float4 v = ((const float4*)s)[i];
        bf16x4 o;
        o.x = (bf16_t)v.x; o.y = (bf16_t)v.y; o.z = (bf16_t)v.z; o.w = (bf16_t)v.w;
        ((bf16x4*)d)[i] = o;
    }
}

__global__ __launch_bounds__(256) void k_cvt2(const float* __restrict__ s0,
                                              const float* __restrict__ s1,
                                              bf16_t* __restrict__ dst, int n4) {
    const float* s = (blockIdx.y == 0) ? s0 : s1;
    bf16_t* d = dst + (size_t)blockIdx.y * ((size_t)n4 * 4);
    int i = blockIdx.x * 256 + threadIdx.x;
    if (i < n4) {
        float4 v = ((const float4*)s)[i];
        bf16x4 o;
        o.x = (bf16_t)v.x; o.y = (bf16_t)v.y; o.z = (bf16_t)v.z; o.w = (bf16_t)v.w;
        ((bf16x4*)d)[i] = o;
    }
}

// ---------------- LayerNorm (one block per row of C=768), bf16 out ----------------
__global__ __launch_bounds__(256) void k_ln(const float* __restrict__ x,
                                            const float* __restrict__ w,
                                            const float* __restrict__ b,
                                            bf16_t* __restrict__ out, int C) {
    int row = blockIdx.x;
    const float* xr = x + (long)row * C;
    int tid = threadIdx.x;
    float s = 0.f, s2 = 0.f;
    for (int i = tid; i < C; i += 256) { float v = xr[i]; s += v; s2 += v * v; }
    for (int m = 32; m; m >>= 1) { s += __shfl_xor(s, m, 64); s2 += __shfl_xor(s2, m, 64); }
    __shared__ float red[8];
    int wv = tid >> 6;
    if ((tid & 63) == 0) { red[wv] = s; red[4 + wv] = s2; }
    __syncthreads();
    float ts  = red[0] + red[1] + red[2] + red[3];
    float ts2 = red[4] + red[5] + red[6] + red[7];
    float mu  = ts / C;
    float var = ts2 / C - mu * mu;
    float rstd = rsqrtf(var + LN_EPS);
    bf16_t* orow = out + (long)row * C;
    for (int i = tid; i < C; i += 256)
        orow[i] = (bf16_t)((xr[i] - mu) * rstd * w[i] + b[i]);
}

// ---------------- bf16 MFMA GEMM: 256x256 tile, 8 waves, 4-buffer counted-vmcnt ----
// C[M][N](+=) A[M][Kslice] * Bw[N][Kslice]^T.  512 threads = 8 waves (2M x 4N),
// per-wave out 128x64 (acc 8x4 frags), BK=32, Kloc=768 -> 24 K-tiles.
// LDS: As[4][256][32] + Bs[4][256][32] = 128 KiB (one block/CU).
// Pipeline: lookahead 2 K-tiles; per iter: s_waitcnt vmcnt(4) [own 4 loads of the
// current K-tile done; next K-tile's 4 stay in flight] + s_barrier; then STAGE(s+2)
// + 12 ds_read_b128 + 32 MFMA. Only the last iter drains vmcnt(0).
// LDS bank swizzle (free 2-way): slot p holds logical slot p ^ ((row>>2)&3);
// stage pre-swizzles the GLOBAL source column (LDS dest stays linear, rule 21).
// EPI 0: store bf16   EPI 1: store bf16(relu^2)   EPI 3: atomicAdd fp32
template <int EPI>
__global__ __launch_bounds__(512, 2) void k_gemm_bt(const bf16_t* __restrict__ A,
                                                    const bf16_t* __restrict__ Bw,
                                                    void* __restrict__ Cout,
                                                    int N, int Ktot, int nbn, int nks) {
    constexpr int TBUF = 256 * 32;                    // elements per buffer (16 KB)
    __shared__ __align__(16) bf16_t As[4][256][32];   // 64 KB
    __shared__ __align__(16) bf16_t Bs[4][256][32];   // 64 KB
    const int tid  = threadIdx.x;
    const int lane = tid & 63, wid = tid >> 6;        // wid 0..7
    const int wm = (wid >> 2) * 128, wn = (wid & 3) * 64;

    // XCD swizzle: grid == 192 (192 % 8 == 0), 24 consecutive tiles per XCD
    int bid = blockIdx.x;
    int swz = (bid & 7) * 24 + (bid >> 3);
    int per_m = nbn * nks;
    int bm  = swz / per_m;
    int rem = swz % per_m;
    int ks  = rem / nbn;
    int bn  = rem % nbn;

    const int fr = lane & 15;
    // read: physical slot = k-octet ^ ((row>>2)&3); (row>>2)&3 == (lane>>2)&3
    const int swcol = (((lane >> 4) ^ (lane >> 2)) & 3) * 8;

    f32x4 acc[8][4];
#pragma unroll
    for (int i = 0; i < 8; i++)
#pragma unroll
        for (int j = 0; j < 4; j++) acc[i][j] = (f32x4){0.f, 0.f, 0.f, 0.f};

    // staging: wave w stages rows [w*32, w*32+32) of A and B: 2 glds16 each (16 rows/glds).
    // lane l -> LDS row base+ (l>>2), physical slot l&3; source logical slot (l&3)^((l>>4)&3)
    const int srow = wid * 32 + (lane >> 2);
    const int scol = (((lane & 3) ^ (lane >> 4)) & 3) * 8;
    const bf16_t* Ag = A  + (size_t)(bm * 256 + srow) * Ktot + (size_t)ks * 768 + scol;
    const bf16_t* Bg = Bw + (size_t)(bn * 256 + srow) * Ktot + (size_t)ks * 768 + scol;
    const size_t Kt16 = (size_t)16 * Ktot;
    bf16_t* lA = &As[0][wid * 32][0];    // wave-uniform LDS bases
    bf16_t* lB = &Bs[0][wid * 32][0];

#define STAGE(buf, kt)                                            \
    do {                                                          \
        const bf16_t* a0 = Ag + (size_t)(kt) * 32;                \
        const bf16_t* b0 = Bg + (size_t)(kt) * 32;                \
        glds16(a0,        lA + (buf) * TBUF);                     \
        glds16(a0 + Kt16, lA + (buf) * TBUF + 16 * 32);           \
        glds16(b0,        lB + (buf) * TBUF);                     \
        glds16(b0 + Kt16, lB + (buf) * TBUF + 16 * 32);           \
    } while (0)

#define COMPUTE(buf)                                                                         \
    do {                                                                                     \
        const bf16_t* pA = &As[0][0][0] + (buf) * TBUF + (wm + fr) * 32 + swcol;             \
        const bf16_t* pB = &Bs[0][0][0] + (buf) * TBUF + (wn + fr) * 32 + swcol;             \
        bf16x8 af[8], bfr[4];                                                                \
        _Pragma("unroll")                                                                    \
        for (int mi = 0; mi < 8; mi++) af[mi] = *(const bf16x8*)(pA + mi * 512);             \
        _Pragma("unroll")                                                                    \
        for (int ni = 0; ni < 4; ni++) bfr[ni] = *(const bf16x8*)(pB + ni * 512);            \
        __builtin_amdgcn_s_setprio(1);                                                       \
        _Pragma("unroll")                                                                    \
        for (int mi = 0; mi < 8; mi++)                                                       \
            _Pragma("unroll")                                                                \
            for (int ni = 0; ni < 4; ni++)                                                   \
                acc[mi][ni] = __builtin_amdgcn_mfma_f32_16x16x32_bf16(af[mi], bfr[ni], acc[mi][ni], 0, 0, 0); \
        __builtin_amdgcn_s_setprio(0);                                                       \
    } while (0)

    // 24 K-tiles of BK=32 (Kloc = 768), lookahead 2
    STAGE(0, 0);
    STAGE(1, 1);
    for (int s = 0; s < 22; ++s) {
        asm volatile("s_waitcnt vmcnt(4)" ::: "memory");  // own loads of K-tile s landed
        __builtin_amdgcn_s_barrier();                     // -> ALL waves' loads landed
        __builtin_amdgcn_sched_barrier(0);
        STAGE((s + 2) & 3, s + 2);
        COMPUTE(s & 3);
    }
    asm volatile("s_waitcnt vmcnt(4)" ::: "memory");
    __builtin_amdgcn_s_barrier();
    __builtin_amdgcn_sched_barrier(0);
    COMPUTE(2);
    asm volatile("s_waitcnt vmcnt(0)" ::: "memory");
    __builtin_amdgcn_s_barrier();
    __builtin_amdgcn_sched_barrier(0);
    COMPUTE(3);

#undef STAGE
#undef COMPUTE

    const int row0 = bm * 256 + wm, col0 = bn * 256 + wn;
#pragma unroll
    for (int mi = 0; mi < 8; mi++) {
#pragma unroll
        for (int ni = 0; ni < 4; ni++) {
            int row = row0 + mi * 16 + (lane >> 4) * 4;   // C/D: col=lane&15, row=(lane>>4)*4+r
            int col = col0 + ni * 16 + (lane & 15);
#pragma unroll
            for (int r = 0; r < 4; r++) {
                float val = acc[mi][ni][r];
                size_t off = (size_t)(row + r) * N + col;
                if (EPI == 0) {
                    ((bf16_t*)Cout)[off] = (bf16_t)val;
                } else if (EPI == 1) {
                    float t = fmaxf(val, 0.f);
                    ((bf16_t*)Cout)[off] = (bf16_t)(t * t);
                } else {
                    atomicAdd(&((float*)Cout)[off], val);
                }
            }
        }
    }
}

// ---------------- WKV chunked scan (y4 bf16) ----------------
// y4 layout per (b,t): [ r(768) | k(768) | v(768) | router(768) ]
__global__ __launch_bounds__(256) void k_scan_local(const bf16_t* __restrict__ y4,
                                                    const float* __restrict__ tmw,
                                                    float* __restrict__ wkvl,
                                                    float* __restrict__ states) {
    int idx = blockIdx.x * 256 + threadIdx.x;  // (b*16 + ch)*768 + c
    int c   = idx % 768;
    int rem = idx / 768;
    int ch  = rem & 15;
    int b   = rem >> 4;
    float d = expf(-expf(tmw[c]));
    const bf16_t* base = y4 + ((size_t)(b * 512 + ch * 32)) * 3072 + c;
    float*        wout = wkvl + ((size_t)(b * 512 + ch * 32)) * 768 + c;
    float s = 0.f;
#pragma unroll 4
    for (int i = 0; i < 32; i++) {
        float kk = (float)base[(size_t)i * 3072 + 768];
        float vv = (float)base[(size_t)i * 3072 + 1536];
        s = s * d + kk * vv;
        wout[(size_t)i * 768] = s;
    }
    states[idx] = s;
}

__global__ __launch_bounds__(256) void k_scan_carry(const float* __restrict__ states,
                                                    const float* __restrict__ tmw,
                                                    float* __restrict__ carries) {
    int idx = blockIdx.x * 256 + threadIdx.x;  // b*768 + c
    int c = idx % 768, b = idx / 768;
    float dL = expf(-expf(tmw[c]) * 32.f);
    float s = 0.f;
    for (int ch = 0; ch < 16; ch++) {
        size_t o = ((size_t)(b * 16 + ch)) * 768 + c;
        carries[o] = s;
        s = s * dL + states[o];
    }
}

// ---------------- mix + LN2 fused: one block per (b,t) row ----------------
// out = x + r*((wkv_local + carry*d^(tmod+1)) * sigmoid(router));  xx2 = LN2(out) bf16
// (out is d_out; the final GEMM atomically adds the channel-mix on top)
__global__ __launch_bounds__(256) void k_mix_ln(const bf16_t* __restrict__ y4,
                                                const float* __restrict__ wkvl,
                                                const float* __restrict__ carries,
                                                const float* __restrict__ tmw,
                                                const float* __restrict__ x,
                                                const float* __restrict__ w2,
                                                const float* __restrict__ b2,
                                                float* __restrict__ out,
                                                bf16_t* __restrict__ xx2) {
    int bt = blockIdx.x;
    int t = bt & 511, b = bt >> 9;
    int tid = threadIdx.x;
    const bf16_t* yrow = y4 + (size_t)bt * 3072;
    const float*  wl   = wkvl + (size_t)bt * 768;
    const float*  cr   = carries + ((size_t)(b * 16) + (t >> 5)) * 768;
    const float*  xr   = x + (size_t)bt * 768;
    float tn = (float)((t & 31) + 1);

    float vals[3];
    float s = 0.f, s2 = 0.f;
#pragma unroll
    for (int j = 0; j < 3; j++) {
        int c = tid + j * 256;
        float rr = (float)yrow[c];
        float gg = (float)yrow[c + 2304];
        float wk = wl[c] + cr[c] * expf(-expf(tmw[c]) * tn);
        float sig = 1.f / (1.f + expf(-gg));
        float o = fmaf(rr, wk * sig, xr[c]);
        vals[j] = o; s += o; s2 += o * o;
    }
    for (int m = 32; m; m >>= 1) { s += __shfl_xor(s, m, 64); s2 += __shfl_xor(s2, m, 64); }
    __shared__ float red[8];
    int wv = tid >> 6;
    if ((tid & 63) == 0) { red[wv] = s; red[4 + wv] = s2; }
    __syncthreads();
    float ts  = red[0] + red[1] + red[2] + red[3];
    float ts2 = red[4] + red[5] + red[6] + red[7];
    float mu  = ts * (1.f / 768.f);
    float var = ts2 * (1.f / 768.f) - mu * mu;
    float rstd = rsqrtf(var + LN_EPS);
    float* orow = out + (size_t)bt * 768;
    bf16_t* xo = xx2 + (size_t)bt * 768;
#pragma unroll
    for (int j = 0; j < 3; j++) {
        int c = tid + j * 256;
        orow[c] = vals[j];
        xo[c] = (bf16_t)((vals[j] - mu) * rstd * w2[c] + b2[c]);
    }
}

// ---------------- host-side launch ----------------
extern "C" void kernel_launch(void* const* d_in, const int* in_sizes, int n_in,
                              void* d_out, int out_size, void* d_ws, size_t ws_size,
                              hipStream_t stream) {
    const float* x    = (const float*)d_in[0];
    const float* ln1w = (const float*)d_in[1];
    const float* ln1b = (const float*)d_in[2];
    const float* Wr   = (const float*)d_in[3];
    const float* Wk   = (const float*)d_in[4];
    const float* Wv   = (const float*)d_in[5];
    const float* tmw  = (const float*)d_in[6];
    const float* Wrt  = (const float*)d_in[7];
    const float* ln2w = (const float*)d_in[8];
    const float* ln2b = (const float*)d_in[9];
    const float* Wck  = (const float*)d_in[10];
    const float* Wcv  = (const float*)d_in[11];
    float* out = (float*)d_out;
    char* ws = (char*)d_ws;

    // workspace layout (bytes)
    bf16_t* xx     = (bf16_t*)(ws + 0);          // 4096*768 bf16 (xx, reused as xx2)
    bf16_t* wcat   = (bf16_t*)(ws + 6291456);    // [4][768][768] bf16 (r,k,v,router)
    bf16_t* wckb   = (bf16_t*)(ws + 11010048);   // [3072][768] bf16
    bf16_t* wcvb   = (bf16_t*)(ws + 15728640);   // [768][3072] bf16
    bf16_t* y4     = (bf16_t*)(ws + 20447232);   // [4096][3072] bf16
    bf16_t* kcm    = (bf16_t*)(ws + 20447232);   // reuses y4 after mix
    float*  wkvl   = (float*)(ws + 70778880);    // [4096][768] fp32
    float*  states = (float*)(ws + 83361792);    // [8][16][768]
    float*  carr   = (float*)(ws + 83755008);    // [8][16][768]

    // 1) weights -> bf16
    const int n768 = 768 * 768 / 4;
    const int nbig = 3072 * 768 / 4;
    k_cvt4<<<dim3(576, 4), dim3(256), 0, stream>>>(Wr, Wk, Wv, Wrt, wcat, n768);
    k_cvt2<<<dim3(2304, 2), dim3(256), 0, stream>>>(Wck, Wcv, wckb, nbig);

    // 2) LN1
    k_ln<<<dim3(4096), dim3(256), 0, stream>>>(x, ln1w, ln1b, xx, 768);

    // 3) fused r|k|v|router GEMM: y4 = xx @ wcat^T  (M=4096, N=3072, Ktot=768)
    k_gemm_bt<0><<<dim3(192), dim3(512), 0, stream>>>(xx, wcat, (void*)y4, 3072, 768, 12, 1);

    // 4) wkv scan + mix(+LN2): writes x1 -> d_out, xx2 -> xx
    k_scan_local<<<dim3(384), dim3(256), 0, stream>>>(y4, tmw, wkvl, states);
    k_scan_carry<<<dim3(24), dim3(256), 0, stream>>>(states, tmw, carr);
    k_mix_ln<<<dim3(4096), dim3(256), 0, stream>>>(y4, wkvl, carr, tmw, x, ln2w, ln2b, out, xx);

    // 5) k_cm = bf16(relu(xx2 @ Wck^T)^2)  (M=4096, N=3072, Ktot=768)
    k_gemm_bt<1><<<dim3(192), dim3(512), 0, stream>>>(xx, wckb, (void*)kcm, 3072, 768, 12, 1);

    // 6) out += k_cm @ Wcv^T  (M=4096, N=768, Ktot=3072), split-K=4, fp32 atomics
    k_gemm_bt<3><<<dim3(192), dim3(512), 0, stream>>>(kcm, wcvb, (void*)out, 768, 3072, 3, 4);
}

// Round 7
// 179.659 us; speedup vs baseline: 1.0129x; 1.0129x over previous
//
#include <hip/hip_runtime.h>
#include <hip/hip_bf16.h>

typedef __bf16 bf16_t;
typedef __bf16 bf16x8 __attribute__((ext_vector_type(8)));
typedef __bf16 bf16x4 __attribute__((ext_vector_type(4)));
typedef __bf16 bf16x2 __attribute__((ext_vector_type(2)));
typedef float  f32x4  __attribute__((ext_vector_type(4)));

#define LN_EPS 1e-5f

// B=8, T=512, C=768 -> M = 4096, 4C = 3072

// ---------------- async global->LDS helper (16B per lane, wave-uniform LDS base) ----
typedef __attribute__((address_space(1))) void gvoid_t;
typedef __attribute__((address_space(3))) void lvoid_t;
__device__ __forceinline__ void glds16(const void* g, void* l) {
    __builtin_amdgcn_global_load_lds((gvoid_t*)g, (lvoid_t*)l, 16, 0, 0);
}

// ---------------- fp32 -> bf16 conversion ----------------
__global__ __launch_bounds__(256) void k_cvt4(const float* __restrict__ s0,
                                              const float* __restrict__ s1,
                                              const float* __restrict__ s2,
                                              const float* __restrict__ s3,
                                              bf16_t* __restrict__ dst, int n4) {
    const float* s = (blockIdx.y == 0) ? s0 : (blockIdx.y == 1) ? s1 : (blockIdx.y == 2) ? s2 : s3;
    bf16_t* d = dst + (size_t)blockIdx.y * ((size_t)n4 * 4);
    int i = blockIdx.x * 256 + threadIdx.x;
    if (i < n4) {
        float4 v = ((const float4*)s)[i];
        bf16x4 o;
        o.x = (bf16_t)v.x; o.y = (bf16_t)v.y; o.z = (bf16_t)v.z; o.w = (bf16_t)v.w;
        ((bf16x4*)d)[i] = o;
    }
}

__global__ __launch_bounds__(256) void k_cvt2(const float* __restrict__ s0,
                                              const float* __restrict__ s1,
                                              bf16_t* __restrict__ dst, int n4) {
    const float* s = (blockIdx.y == 0) ? s0 : s1;
    bf16_t* d = dst + (size_t)blockIdx.y * ((size_t)n4 * 4);
    int i = blockIdx.x * 256 + threadIdx.x;
    if (i < n4) {
        float4 v = ((const float4*)s)[i];
        bf16x4 o;
        o.x = (bf16_t)v.x; o.y = (bf16_t)v.y; o.z = (bf16_t)v.z; o.w = (bf16_t)v.w;
        ((bf16x4*)d)[i] = o;
    }
}

// ---------------- LayerNorm (one block per row of C=768), bf16 out ----------------
__global__ __launch_bounds__(256) void k_ln(const float* __restrict__ x,
                                            const float* __restrict__ w,
                                            const float* __restrict__ b,
                                            bf16_t* __restrict__ out, int C) {
    int row = blockIdx.x;
    const float* xr = x + (long)row * C;
    int tid = threadIdx.x;
    float s = 0.f, s2 = 0.f;
    for (int i = tid; i < C; i += 256) { float v = xr[i]; s += v; s2 += v * v; }
    for (int m = 32; m; m >>= 1) { s += __shfl_xor(s, m, 64); s2 += __shfl_xor(s2, m, 64); }
    __shared__ float red[8];
    int wv = tid >> 6;
    if ((tid & 63) == 0) { red[wv] = s; red[4 + wv] = s2; }
    __syncthreads();
    float ts  = red[0] + red[1] + red[2] + red[3];
    float ts2 = red[4] + red[5] + red[6] + red[7];
    float mu  = ts / C;
    float var = ts2 / C - mu * mu;
    float rstd = rsqrtf(var + LN_EPS);
    bf16_t* orow = out + (long)row * C;
    for (int i = tid; i < C; i += 256)
        orow[i] = (bf16_t)((xr[i] - mu) * rstd * w[i] + b[i]);
}

// ---------------- bf16 MFMA GEMM: 64x128 tile, 4 waves, dbuf, full co-residency ----
// C[M][N](+=) A[M][Kslice] * Bw[N][Kslice]^T.  256 threads = 4 waves (2M x 2N),
// per-wave out 32x64 (acc 2x4), BK=32, Kloc=768 -> 24 K-tiles.
// LDS = 2 x (64+128) x 32 x 2B = 24 KB -> 6 blocks/CU; grid 1536 = 6*256 (all
// co-resident: per-block exposed latency hidden by 6-way block TLP — the only
// mechanism that moved the needle across R2-R6).
// Staging: 3 glds16/wave (A 16 rows + B 32 rows); LDS swizzle: free 2-way XOR,
// physical chunk = logical ^ ((row>>2)&3); stage pre-swizzles the GLOBAL source
// column, LDS dest stays linear (rule 21); read applies the same XOR.
// XCD slab: 8 slabs of 16bm x 12cols -> per-XCD L2 set ~3.9MB <= 4MB.
// EPI 0: store bf16   EPI 1: store bf16(relu^2)   EPI 3: atomicAdd fp32
template <int EPI>
__global__ __launch_bounds__(256, 6) void k_gemm_bt(const bf16_t* __restrict__ A,
                                                    const bf16_t* __restrict__ Bw,
                                                    void* __restrict__ Cout,
                                                    int N, int Ktot, int nbn, int nks) {
    constexpr int ABUF = 64 * 32;                    // elems per A buffer (4 KB)
    constexpr int BBUF = 128 * 32;                   // elems per B buffer (8 KB)
    __shared__ __align__(16) bf16_t As[2][64][32];   // 8 KB
    __shared__ __align__(16) bf16_t Bs[2][128][32];  // 16 KB
    const int tid  = threadIdx.x;
    const int lane = tid & 63, wid = tid >> 6;       // wid 0..3
    const int wm = (wid >> 1) * 32, wn = (wid & 1) * 64;

    // XCD slab swizzle: grid == 1536; xcd = bid%8; slab = 16 bm x 12 col-units
    int bid = blockIdx.x;
    int xcd = bid & 7, loc = bid >> 3;               // loc 0..191
    int bm  = (xcd >> 1) * 16 + loc / 12;            // 0..63
    int cix = (xcd & 1) * 12 + loc % 12;             // 0..23
    int ks  = cix / nbn;
    int bn  = cix % nbn;

    const int fr = lane & 15;
    // read: physical chunk = k-chunk ^ ((row>>2)&3); (row>>2)&3 == (lane>>2)&3
    const int swcol = (((lane >> 4) ^ (lane >> 2)) & 3) * 8;

    f32x4 acc[2][4];
#pragma unroll
    for (int i = 0; i < 2; i++)
#pragma unroll
        for (int j = 0; j < 4; j++) acc[i][j] = (f32x4){0.f, 0.f, 0.f, 0.f};

    // staging: wave w: A rows [w*16,w*16+16) (1 glds16), B rows [w*32,w*32+32) (2).
    // lane l -> row base+(l>>2), phys chunk l&3; source logical chunk (l&3)^((l>>4)&3)
    const int rsub = lane >> 2;
    const int scol = (((lane & 3) ^ (lane >> 4)) & 3) * 8;
    const bf16_t* Ag = A  + (size_t)(bm * 64  + wid * 16 + rsub) * Ktot + (size_t)ks * 768 + scol;
    const bf16_t* Bg = Bw + (size_t)(bn * 128 + wid * 32 + rsub) * Ktot + (size_t)ks * 768 + scol;
    const size_t Kt16 = (size_t)16 * Ktot;
    bf16_t* lA = &As[0][wid * 16][0];    // wave-uniform LDS bases
    bf16_t* lB = &Bs[0][wid * 32][0];

#define STAGE(buf, kt)                                            \
    do {                                                          \
        const bf16_t* a0 = Ag + (size_t)(kt) * 32;                \
        const bf16_t* b0 = Bg + (size_t)(kt) * 32;                \
        glds16(a0,        lA + (buf) * ABUF);                     \
        glds16(b0,        lB + (buf) * BBUF);                     \
        glds16(b0 + Kt16, lB + (buf) * BBUF + 16 * 32);           \
    } while (0)

#define COMPUTE(buf)                                                                         \
    do {                                                                                     \
        const bf16_t* pA = &As[0][0][0] + (buf) * ABUF + (wm + fr) * 32 + swcol;             \
        const bf16_t* pB = &Bs[0][0][0] + (buf) * BBUF + (wn + fr) * 32 + swcol;             \
        bf16x8 af[2], bfr[4];                                                                \
        _Pragma("unroll")                                                                    \
        for (int mi = 0; mi < 2; mi++) af[mi] = *(const bf16x8*)(pA + mi * 512);             \
        _Pragma("unroll")                                                                    \
        for (int ni = 0; ni < 4; ni++) bfr[ni] = *(const bf16x8*)(pB + ni * 512);            \
        __builtin_amdgcn_s_setprio(1);                                                       \
        _Pragma("unroll")                                                                    \
        for (int mi = 0; mi < 2; mi++)                                                       \
            _Pragma("unroll")                                                                \
            for (int ni = 0; ni < 4; ni++)                                                   \
                acc[mi][ni] = __builtin_amdgcn_mfma_f32_16x16x32_bf16(af[mi], bfr[ni], acc[mi][ni], 0, 0, 0); \
        __builtin_amdgcn_s_setprio(0);                                                       \
    } while (0)

    // 24 K-tiles of BK=32 (Kloc = 768), 2-phase: prefetch next, compute cur, drain
    STAGE(0, 0);
    __syncthreads();
    int cur = 0;
    for (int kt = 0; kt < 23; ++kt) {
        STAGE(cur ^ 1, kt + 1);
        COMPUTE(cur);
        __syncthreads();
        cur ^= 1;
    }
    COMPUTE(cur);

#undef STAGE
#undef COMPUTE

    const int row0 = bm * 64 + wm, col0 = bn * 128 + wn;
#pragma unroll
    for (int mi = 0; mi < 2; mi++) {
#pragma unroll
        for (int ni = 0; ni < 4; ni++) {
            int row = row0 + mi * 16 + (lane >> 4) * 4;   // C/D: col=lane&15, row=(lane>>4)*4+r
            int col = col0 + ni * 16 + (lane & 15);
#pragma unroll
            for (int r = 0; r < 4; r++) {
                float val = acc[mi][ni][r];
                size_t off = (size_t)(row + r) * N + col;
                if (EPI == 0) {
                    ((bf16_t*)Cout)[off] = (bf16_t)val;
                } else if (EPI == 1) {
                    float t = fmaxf(val, 0.f);
                    ((bf16_t*)Cout)[off] = (bf16_t)(t * t);
                } else {
                    atomicAdd(&((float*)Cout)[off], val);
                }
            }
        }
    }
}

// ---------------- WKV chunked scan (y4 bf16), 2 channels/thread ----------------
// y4 layout per (b,t): [ r(768) | k(768) | v(768) | router(768) ]
__global__ __launch_bounds__(256) void k_scan_local(const bf16_t* __restrict__ y4,
                                                    const float* __restrict__ tmw,
                                                    float* __restrict__ wkvl,
                                                    float* __restrict__ states) {
    int idx = blockIdx.x * 256 + threadIdx.x;  // 8*16*384 = 49152
    int cp  = idx % 384;
    int rem = idx / 384;
    int ch  = rem & 15;
    int b   = rem >> 4;
    int c   = cp * 2;
    float d0 = expf(-expf(tmw[c]));
    float d1 = expf(-expf(tmw[c + 1]));
    const bf16_t* base = y4 + ((size_t)(b * 512 + ch * 32)) * 3072 + c;
    float*        wout = wkvl + ((size_t)(b * 512 + ch * 32)) * 768 + c;
    float s0 = 0.f, s1 = 0.f;
#pragma unroll 4
    for (int i = 0; i < 32; i++) {
        bf16x2 k2 = *(const bf16x2*)(base + (size_t)i * 3072 + 768);
        bf16x2 v2 = *(const bf16x2*)(base + (size_t)i * 3072 + 1536);
        s0 = s0 * d0 + (float)k2.x * (float)v2.x;
        s1 = s1 * d1 + (float)k2.y * (float)v2.y;
        *(float2*)(wout + (size_t)i * 768) = make_float2(s0, s1);
    }
    *(float2*)(states + ((size_t)(b * 16 + ch)) * 768 + c) = make_float2(s0, s1);
}

__global__ __launch_bounds__(256) void k_scan_carry(const float* __restrict__ states,
                                                    const float* __restrict__ tmw,
                                                    float* __restrict__ carries) {
    int idx = blockIdx.x * 256 + threadIdx.x;  // b*768 + c
    int c = idx % 768, b = idx / 768;
    float dL = expf(-expf(tmw[c]) * 32.f);
    float s = 0.f;
    for (int ch = 0; ch < 16; ch++) {
        size_t o = ((size_t)(b * 16 + ch)) * 768 + c;
        carries[o] = s;
        s = s * dL + states[o];
    }
}

// ---------------- mix + LN2 fused: one block per (b,t) row ----------------
// out = x + r*((wkv_local + carry*d^(tmod+1)) * sigmoid(router));  xx2 = LN2(out) bf16
// (out is d_out; the final GEMM atomically adds the channel-mix on top)
__global__ __launch_bounds__(256) void k_mix_ln(const bf16_t* __restrict__ y4,
                                                const float* __restrict__ wkvl,
                                                const float* __restrict__ carries,
                                                const float* __restrict__ tmw,
                                                const float* __restrict__ x,
                                                const float* __restrict__ w2,
                                                const float* __restrict__ b2,
                                                float* __restrict__ out,
                                                bf16_t* __restrict__ xx2) {
    int bt = blockIdx.x;
    int t = bt & 511, b = bt >> 9;
    int tid = threadIdx.x;
    const bf16_t* yrow = y4 + (size_t)bt * 3072;
    const float*  wl   = wkvl + (size_t)bt * 768;
    const float*  cr   = carries + ((size_t)(b * 16) + (t >> 5)) * 768;
    const float*  xr   = x + (size_t)bt * 768;
    float tn = (float)((t & 31) + 1);

    float vals[3];
    float s = 0.f, s2 = 0.f;
#pragma unroll
    for (int j = 0; j < 3; j++) {
        int c = tid + j * 256;
        float rr = (float)yrow[c];
        float gg = (float)yrow[c + 2304];
        float wk = wl[c] + cr[c] * expf(-expf(tmw[c]) * tn);
        float sig = 1.f / (1.f + expf(-gg));
        float o = fmaf(rr, wk * sig, xr[c]);
        vals[j] = o; s += o; s2 += o * o;
    }
    for (int m = 32; m; m >>= 1) { s += __shfl_xor(s, m, 64); s2 += __shfl_xor(s2, m, 64); }
    __shared__ float red[8];
    int wv = tid >> 6;
    if ((tid & 63) == 0) { red[wv] = s; red[4 + wv] = s2; }
    __syncthreads();
    float ts  = red[0] + red[1] + red[2] + red[3];
    float ts2 = red[4] + red[5] + red[6] + red[7];
    float mu  = ts * (1.f / 768.f);
    float var = ts2 * (1.f / 768.f) - mu * mu;
    float rstd = rsqrtf(var + LN_EPS);
    float* orow = out + (size_t)bt * 768;
    bf16_t* xo = xx2 + (size_t)bt * 768;
#pragma unroll
    for (int j = 0; j < 3; j++) {
        int c = tid + j * 256;
        orow[c] = vals[j];
        xo[c] = (bf16_t)((vals[j] - mu) * rstd * w2[c] + b2[c]);
    }
}

// ---------------- host-side launch ----------------
extern "C" void kernel_launch(void* const* d_in, const int* in_sizes, int n_in,
                              void* d_out, int out_size, void* d_ws, size_t ws_size,
                              hipStream_t stream) {
    const float* x    = (const float*)d_in[0];
    const float* ln1w = (const float*)d_in[1];
    const float* ln1b = (const float*)d_in[2];
    const float* Wr   = (const float*)d_in[3];
    const float* Wk   = (const float*)d_in[4];
    const float* Wv   = (const float*)d_in[5];
    const float* tmw  = (const float*)d_in[6];
    const float* Wrt  = (const float*)d_in[7];
    const float* ln2w = (const float*)d_in[8];
    const float* ln2b = (const float*)d_in[9];
    const float* Wck  = (const float*)d_in[10];
    const float* Wcv  = (const float*)d_in[11];
    float* out = (float*)d_out;
    char* ws = (char*)d_ws;

    // workspace layout (bytes)
    bf16_t* xx     = (bf16_t*)(ws + 0);          // 4096*768 bf16 (xx, reused as xx2)
    bf16_t* wcat   = (bf16_t*)(ws + 6291456);    // [4][768][768] bf16 (r,k,v,router)
    bf16_t* wckb   = (bf16_t*)(ws + 11010048);   // [3072][768] bf16
    bf16_t* wcvb   = (bf16_t*)(ws + 15728640);   // [768][3072] bf16
    bf16_t* y4     = (bf16_t*)(ws + 20447232);   // [4096][3072] bf16
    bf16_t* kcm    = (bf16_t*)(ws + 20447232);   // reuses y4 after mix
    float*  wkvl   = (float*)(ws + 70778880);    // [4096][768] fp32
    float*  states = (float*)(ws + 83361792);    // [8][16][768]
    float*  carr   = (float*)(ws + 83755008);    // [8][16][768]

    // 1) weights -> bf16
    const int n768 = 768 * 768 / 4;
    const int nbig = 3072 * 768 / 4;
    k_cvt4<<<dim3(576, 4), dim3(256), 0, stream>>>(Wr, Wk, Wv, Wrt, wcat, n768);
    k_cvt2<<<dim3(2304, 2), dim3(256), 0, stream>>>(Wck, Wcv, wckb, nbig);

    // 2) LN1
    k_ln<<<dim3(4096), dim3(256), 0, stream>>>(x, ln1w, ln1b, xx, 768);

    // 3) fused r|k|v|router GEMM: y4 = xx @ wcat^T  (M=4096, N=3072, Ktot=768)
    k_gemm_bt<0><<<dim3(1536), dim3(256), 0, stream>>>(xx, wcat, (void*)y4, 3072, 768, 24, 1);

    // 4) wkv scan + mix(+LN2): writes x1 -> d_out, xx2 -> xx
    k_scan_local<<<dim3(192), dim3(256), 0, stream>>>(y4, tmw, wkvl, states);
    k_scan_carry<<<dim3(24), dim3(256), 0, stream>>>(states, tmw, carr);
    k_mix_ln<<<dim3(4096), dim3(256), 0, stream>>>(y4, wkvl, carr, tmw, x, ln2w, ln2b, out, xx);

    // 5) k_cm = bf16(relu(xx2 @ Wck^T)^2)  (M=4096, N=3072, Ktot=768)
    k_gemm_bt<1><<<dim3(1536), dim3(256), 0, stream>>>(xx, wckb, (void*)kcm, 3072, 768, 24, 1);

    // 6) out += k_cm @ Wcv^T  (M=4096, N=768, Ktot=3072), split-K=4, fp32 atomics
    k_gemm_bt<3><<<dim3(1536), dim3(256), 0, stream>>>(kcm, wcvb, (void*)out, 768, 3072, 6, 4);
}

// Round 8
// 164.371 us; speedup vs baseline: 1.1071x; 1.0930x over previous
//
#include <hip/hip_runtime.h>
#include <hip/hip_bf16.h>

typedef __bf16 bf16_t;
typedef __bf16 bf16x8 __attribute__((ext_vector_type(8)));
typedef __bf16 bf16x4 __attribute__((ext_vector_type(4)));
typedef __bf16 bf16x2 __attribute__((ext_vector_type(2)));
typedef float  f32x4  __attribute__((ext_vector_type(4)));

#define LN_EPS 1e-5f

// B=8, T=512, C=768 -> M = 4096, 4C = 3072

// ---------------- async global->LDS helper (16B per lane, wave-uniform LDS base) ----
typedef __attribute__((address_space(1))) void gvoid_t;
typedef __attribute__((address_space(3))) void lvoid_t;
__device__ __forceinline__ void glds16(const void* g, void* l) {
    __builtin_amdgcn_global_load_lds((gvoid_t*)g, (lvoid_t*)l, 16, 0, 0);
}

// ---------------- fp32 -> bf16 conversion ----------------
__global__ __launch_bounds__(256) void k_cvt4(const float* __restrict__ s0,
                                              const float* __restrict__ s1,
                                              const float* __restrict__ s2,
                                              const float* __restrict__ s3,
                                              bf16_t* __restrict__ dst, int n4) {
    const float* s = (blockIdx.y == 0) ? s0 : (blockIdx.y == 1) ? s1 : (blockIdx.y == 2) ? s2 : s3;
    bf16_t* d = dst + (size_t)blockIdx.y * ((size_t)n4 * 4);
    int i = blockIdx.x * 256 + threadIdx.x;
    if (i < n4) {
        float4 v = ((const float4*)s)[i];
        bf16x4 o;
        o.x = (bf16_t)v.x; o.y = (bf16_t)v.y; o.z = (bf16_t)v.z; o.w = (bf16_t)v.w;
        ((bf16x4*)d)[i] = o;
    }
}

__global__ __launch_bounds__(256) void k_cvt2(const float* __restrict__ s0,
                                              const float* __restrict__ s1,
                                              bf16_t* __restrict__ dst, int n4) {
    const float* s = (blockIdx.y == 0) ? s0 : s1;
    bf16_t* d = dst + (size_t)blockIdx.y * ((size_t)n4 * 4);
    int i = blockIdx.x * 256 + threadIdx.x;
    if (i < n4) {
        float4 v = ((const float4*)s)[i];
        bf16x4 o;
        o.x = (bf16_t)v.x; o.y = (bf16_t)v.y; o.z = (bf16_t)v.z; o.w = (bf16_t)v.w;
        ((bf16x4*)d)[i] = o;
    }
}

// ---------------- LayerNorm (one block per row of C=768), bf16 out ----------------
__global__ __launch_bounds__(256) void k_ln(const float* __restrict__ x,
                                            const float* __restrict__ w,
                                            const float* __restrict__ b,
                                            bf16_t* __restrict__ out, int C) {
    int row = blockIdx.x;
    const float* xr = x + (long)row * C;
    int tid = threadIdx.x;
    float s = 0.f, s2 = 0.f;
    for (int i = tid; i < C; i += 256) { float v = xr[i]; s += v; s2 += v * v; }
    for (int m = 32; m; m >>= 1) { s += __shfl_xor(s, m, 64); s2 += __shfl_xor(s2, m, 64); }
    __shared__ float red[8];
    int wv = tid >> 6;
    if ((tid & 63) == 0) { red[wv] = s; red[4 + wv] = s2; }
    __syncthreads();
    float ts  = red[0] + red[1] + red[2] + red[3];
    float ts2 = red[4] + red[5] + red[6] + red[7];
    float mu  = ts / C;
    float var = ts2 / C - mu * mu;
    float rstd = rsqrtf(var + LN_EPS);
    bf16_t* orow = out + (long)row * C;
    for (int i = tid; i < C; i += 256)
        orow[i] = (bf16_t)((xr[i] - mu) * rstd * w[i] + b[i]);
}

// ---------------- bf16 MFMA GEMM: 256x256 tile, BK=64, 8 waves, dbuf 128 KB --------
// C[M][N](+=) A[M][Kslice] * Bw[N][Kslice]^T.  512 threads = 8 waves (2M x 4N),
// per-wave out 128x64 (acc 8x4 of 16x16 frags), 12 K-tiles of BK=64.
// Traffic: 256^2 tile cuts L2/L3 re-read 3x vs 128^2 (the R2-R7 wall: 442 MB @
// ~7 TB/s L3). Per-tile compute ~2480 cyc >> load latency, so the early-issued
// STAGE(t+1) fully retires under COMPUTE(t): tile-top vmcnt(0) is ~free.
// LDS swizzle (2-way, free): 128-B rows = 8 16B-slots; LDS[row][p] holds
// A[row][p ^ (row&7)] via pre-swizzled GLOBAL source col (dest linear, rule 21);
// reads XOR the same pattern. XCD slab 4bm x 6cix -> ~3.9 MB L2 set.
// EPI 0: store bf16   EPI 1: store bf16(relu^2)   EPI 3: atomicAdd fp32
template <int EPI>
__global__ __launch_bounds__(512, 2) void k_gemm_bt(const bf16_t* __restrict__ A,
                                                    const bf16_t* __restrict__ Bw,
                                                    void* __restrict__ Cout,
                                                    int N, int Ktot, int nbn, int nks) {
    constexpr int TBUF = 256 * 64;                    // elems per buffer (32 KB)
    __shared__ __align__(16) bf16_t As[2][256][64];   // 64 KB
    __shared__ __align__(16) bf16_t Bs[2][256][64];   // 64 KB
    const int tid  = threadIdx.x;
    const int lane = tid & 63, wid = tid >> 6;        // wid 0..7
    const int wm = (wid >> 2) * 128, wn = (wid & 3) * 64;

    // XCD slab swizzle: grid == 192; xcd = bid%8 gets 24 blocks = 4 bm x 6 cix
    int bid = blockIdx.x;
    int xcd = bid & 7, loc = bid >> 3;                // loc 0..23
    int bm  = (xcd >> 1) * 4 + loc / 6;               // 0..15
    int cix = (xcd & 1) * 6 + loc % 6;                // 0..11
    int ks  = cix / nbn;
    int bn  = cix % nbn;

    const int fr  = lane & 15;
    const int oct = lane >> 4;                        // 0..3
    // read phys 16B-slot for kk in {0,1}: (kk*4 + oct) ^ (fr&7)  -> 2-way, free
    const int ph0 = ((oct)     ^ (fr & 7)) * 8;       // elems
    const int ph1 = ((oct + 4) ^ (fr & 7)) * 8;

    f32x4 acc[8][4];
#pragma unroll
    for (int i = 0; i < 8; i++)
#pragma unroll
        for (int j = 0; j < 4; j++) acc[i][j] = (f32x4){0.f, 0.f, 0.f, 0.f};

    // staging: wave w stages rows [w*32, w*32+32) of A and B: 4 glds16 each (8 rows/glds).
    // lane l -> row +(l>>3), phys slot l&7; source logical slot (l&7)^(l>>3)
    const int srow = wid * 32 + (lane >> 3);
    const int scol = ((lane & 7) ^ (lane >> 3)) * 8;  // pre-swizzled source col (elems)
    const size_t ksoff = (size_t)ks * 768;
    const bf16_t* Ag = A  + (size_t)(bm * 256 + srow) * Ktot + ksoff + scol;
    const bf16_t* Bg = Bw + (size_t)(bn * 256 + srow) * Ktot + ksoff + scol;
    const size_t Kt8 = (size_t)8 * Ktot;
    bf16_t* lA = &As[0][0][0] + (size_t)(wid * 32) * 64;   // wave-uniform LDS bases
    bf16_t* lB = &Bs[0][0][0] + (size_t)(wid * 32) * 64;

#define STAGE(buf, kt)                                                     \
    do {                                                                   \
        const bf16_t* a0 = Ag + (size_t)(kt) * 64;                         \
        const bf16_t* b0 = Bg + (size_t)(kt) * 64;                         \
        _Pragma("unroll")                                                  \
        for (int q = 0; q < 4; q++) {                                      \
            glds16(a0 + q * Kt8, lA + (buf) * TBUF + q * 512);             \
            glds16(b0 + q * Kt8, lB + (buf) * TBUF + q * 512);             \
        }                                                                  \
    } while (0)

#define COMPUTE_KK(buf, PH, KOFF)                                                            \
    do {                                                                                     \
        const bf16_t* bA = &As[0][0][0] + (buf) * TBUF;                                      \
        const bf16_t* bB = &Bs[0][0][0] + (buf) * TBUF;                                      \
        bf16x8 bfr[4], af[8];                                                                \
        _Pragma("unroll")                                                                    \
        for (int ni = 0; ni < 4; ni++)                                                       \
            bfr[ni] = *(const bf16x8*)(bB + (wn + ni * 16 + fr) * 64 + (PH));                \
        _Pragma("unroll")                                                                    \
        for (int mi = 0; mi < 8; mi++)                                                       \
            af[mi] = *(const bf16x8*)(bA + (wm + mi * 16 + fr) * 64 + (PH));                 \
        __builtin_amdgcn_s_setprio(1);                                                       \
        _Pragma("unroll")                                                                    \
        for (int mi = 0; mi < 8; mi++)                                                       \
            _Pragma("unroll")                                                                \
            for (int ni = 0; ni < 4; ni++)                                                   \
                acc[mi][ni] = __builtin_amdgcn_mfma_f32_16x16x32_bf16(af[mi], bfr[ni], acc[mi][ni], 0, 0, 0); \
        __builtin_amdgcn_s_setprio(0);                                                       \
    } while (0)

    // 12 K-tiles of BK=64 (Kloc = 768), dbuf, early-stage, one barrier per tile
    STAGE(0, 0);
    for (int t = 0; t < 12; ++t) {
        asm volatile("s_waitcnt vmcnt(0)" ::: "memory");   // stage(t) landed (early-issued)
        __builtin_amdgcn_s_barrier();                      // all waves' stage(t) visible
        __builtin_amdgcn_sched_barrier(0);
        if (t < 11) STAGE((t + 1) & 1, t + 1);             // retires under ~2480cyc compute
        __builtin_amdgcn_sched_barrier(0);
        COMPUTE_KK(t & 1, ph0, 0);                         // kk=0 (cols 0-31)
        COMPUTE_KK(t & 1, ph1, 32);                        // kk=1 (cols 32-63)
    }

#undef STAGE
#undef COMPUTE_KK

    const int row0 = bm * 256 + wm, col0 = bn * 256 + wn;
#pragma unroll
    for (int mi = 0; mi < 8; mi++) {
#pragma unroll
        for (int ni = 0; ni < 4; ni++) {
            int row = row0 + mi * 16 + (lane >> 4) * 4;   // C/D: col=lane&15, row=(lane>>4)*4+r
            int col = col0 + ni * 16 + (lane & 15);
#pragma unroll
            for (int r = 0; r < 4; r++) {
                float val = acc[mi][ni][r];
                size_t off = (size_t)(row + r) * N + col;
                if (EPI == 0) {
                    ((bf16_t*)Cout)[off] = (bf16_t)val;
                } else if (EPI == 1) {
                    float t = fmaxf(val, 0.f);
                    ((bf16_t*)Cout)[off] = (bf16_t)(t * t);
                } else {
                    atomicAdd(&((float*)Cout)[off], val);
                }
            }
        }
    }
}

// ---------------- WKV chunked scan (y4 bf16), 2 channels/thread ----------------
// y4 layout per (b,t): [ r(768) | k(768) | v(768) | router(768) ]
__global__ __launch_bounds__(256) void k_scan_local(const bf16_t* __restrict__ y4,
                                                    const float* __restrict__ tmw,
                                                    float* __restrict__ wkvl,
                                                    float* __restrict__ states) {
    int idx = blockIdx.x * 256 + threadIdx.x;  // 8*16*384 = 49152
    int cp  = idx % 384;
    int rem = idx / 384;
    int ch  = rem & 15;
    int b   = rem >> 4;
    int c   = cp * 2;
    float d0 = expf(-expf(tmw[c]));
    float d1 = expf(-expf(tmw[c + 1]));
    const bf16_t* base = y4 + ((size_t)(b * 512 + ch * 32)) * 3072 + c;
    float*        wout = wkvl + ((size_t)(b * 512 + ch * 32)) * 768 + c;
    float s0 = 0.f, s1 = 0.f;
#pragma unroll 4
    for (int i = 0; i < 32; i++) {
        bf16x2 k2 = *(const bf16x2*)(base + (size_t)i * 3072 + 768);
        bf16x2 v2 = *(const bf16x2*)(base + (size_t)i * 3072 + 1536);
        s0 = s0 * d0 + (float)k2.x * (float)v2.x;
        s1 = s1 * d1 + (float)k2.y * (float)v2.y;
        *(float2*)(wout + (size_t)i * 768) = make_float2(s0, s1);
    }
    *(float2*)(states + ((size_t)(b * 16 + ch)) * 768 + c) = make_float2(s0, s1);
}

__global__ __launch_bounds__(256) void k_scan_carry(const float* __restrict__ states,
                                                    const float* __restrict__ tmw,
                                                    float* __restrict__ carries) {
    int idx = blockIdx.x * 256 + threadIdx.x;  // b*768 + c
    int c = idx % 768, b = idx / 768;
    float dL = expf(-expf(tmw[c]) * 32.f);
    float s = 0.f;
    for (int ch = 0; ch < 16; ch++) {
        size_t o = ((size_t)(b * 16 + ch)) * 768 + c;
        carries[o] = s;
        s = s * dL + states[o];
    }
}

// ---------------- mix + LN2 fused: one block per (b,t) row ----------------
// out = x + r*((wkv_local + carry*d^(tmod+1)) * sigmoid(router));  xx2 = LN2(out) bf16
// (out is d_out; the final GEMM atomically adds the channel-mix on top)
__global__ __launch_bounds__(256) void k_mix_ln(const bf16_t* __restrict__ y4,
                                                const float* __restrict__ wkvl,
                                                const float* __restrict__ carries,
                                                const float* __restrict__ tmw,
                                                const float* __restrict__ x,
                                                const float* __restrict__ w2,
                                                const float* __restrict__ b2,
                                                float* __restrict__ out,
                                                bf16_t* __restrict__ xx2) {
    int bt = blockIdx.x;
    int t = bt & 511, b = bt >> 9;
    int tid = threadIdx.x;
    const bf16_t* yrow = y4 + (size_t)bt * 3072;
    const float*  wl   = wkvl + (size_t)bt * 768;
    const float*  cr   = carries + ((size_t)(b * 16) + (t >> 5)) * 768;
    const float*  xr   = x + (size_t)bt * 768;
    float tn = (float)((t & 31) + 1);

    float vals[3];
    float s = 0.f, s2 = 0.f;
#pragma unroll
    for (int j = 0; j < 3; j++) {
        int c = tid + j * 256;
        float rr = (float)yrow[c];
        float gg = (float)yrow[c + 2304];
        float wk = wl[c] + cr[c] * expf(-expf(tmw[c]) * tn);
        float sig = 1.f / (1.f + expf(-gg));
        float o = fmaf(rr, wk * sig, xr[c]);
        vals[j] = o; s += o; s2 += o * o;
    }
    for (int m = 32; m; m >>= 1) { s += __shfl_xor(s, m, 64); s2 += __shfl_xor(s2, m, 64); }
    __shared__ float red[8];
    int wv = tid >> 6;
    if ((tid & 63) == 0) { red[wv] = s; red[4 + wv] = s2; }
    __syncthreads();
    float ts  = red[0] + red[1] + red[2] + red[3];
    float ts2 = red[4] + red[5] + red[6] + red[7];
    float mu  = ts * (1.f / 768.f);
    float var = ts2 * (1.f / 768.f) - mu * mu;
    float rstd = rsqrtf(var + LN_EPS);
    float* orow = out + (size_t)bt * 768;
    bf16_t* xo = xx2 + (size_t)bt * 768;
#pragma unroll
    for (int j = 0; j < 3; j++) {
        int c = tid + j * 256;
        orow[c] = vals[j];
        xo[c] = (bf16_t)((vals[j] - mu) * rstd * w2[c] + b2[c]);
    }
}

// ---------------- host-side launch ----------------
extern "C" void kernel_launch(void* const* d_in, const int* in_sizes, int n_in,
                              void* d_out, int out_size, void* d_ws, size_t ws_size,
                              hipStream_t stream) {
    const float* x    = (const float*)d_in[0];
    const float* ln1w = (const float*)d_in[1];
    const float* ln1b = (const float*)d_in[2];
    const float* Wr   = (const float*)d_in[3];
    const float* Wk   = (const float*)d_in[4];
    const float* Wv   = (const float*)d_in[5];
    const float* tmw  = (const float*)d_in[6];
    const float* Wrt  = (const float*)d_in[7];
    const float* ln2w = (const float*)d_in[8];
    const float* ln2b = (const float*)d_in[9];
    const float* Wck  = (const float*)d_in[10];
    const float* Wcv  = (const float*)d_in[11];
    float* out = (float*)d_out;
    char* ws = (char*)d_ws;

    // workspace layout (bytes)
    bf16_t* xx     = (bf16_t*)(ws + 0);          // 4096*768 bf16 (xx, reused as xx2)
    bf16_t* wcat   = (bf16_t*)(ws + 6291456);    // [4][768][768] bf16 (r,k,v,router)
    bf16_t* wckb   = (bf16_t*)(ws + 11010048);   // [3072][768] bf16
    bf16_t* wcvb   = (bf16_t*)(ws + 15728640);   // [768][3072] bf16
    bf16_t* y4     = (bf16_t*)(ws + 20447232);   // [4096][3072] bf16
    bf16_t* kcm    = (bf16_t*)(ws + 20447232);   // reuses y4 after mix
    float*  wkvl   = (float*)(ws + 70778880);    // [4096][768] fp32
    float*  states = (float*)(ws + 83361792);    // [8][16][768]
    float*  carr   = (float*)(ws + 83755008);    // [8][16][768]

    // 1) weights -> bf16
    const int n768 = 768 * 768 / 4;
    const int nbig = 3072 * 768 / 4;
    k_cvt4<<<dim3(576, 4), dim3(256), 0, stream>>>(Wr, Wk, Wv, Wrt, wcat, n768);
    k_cvt2<<<dim3(2304, 2), dim3(256), 0, stream>>>(Wck, Wcv, wckb, nbig);

    // 2) LN1
    k_ln<<<dim3(4096), dim3(256), 0, stream>>>(x, ln1w, ln1b, xx, 768);

    // 3) fused r|k|v|router GEMM: y4 = xx @ wcat^T  (M=4096, N=3072, Ktot=768)
    k_gemm_bt<0><<<dim3(192), dim3(512), 0, stream>>>(xx, wcat, (void*)y4, 3072, 768, 12, 1);

    // 4) wkv scan + mix(+LN2): writes x1 -> d_out, xx2 -> xx
    k_scan_local<<<dim3(192), dim3(256), 0, stream>>>(y4, tmw, wkvl, states);
    k_scan_carry<<<dim3(24), dim3(256), 0, stream>>>(states, tmw, carr);
    k_mix_ln<<<dim3(4096), dim3(256), 0, stream>>>(y4, wkvl, carr, tmw, x, ln2w, ln2b, out, xx);

    // 5) k_cm = bf16(relu(xx2 @ Wck^T)^2)  (M=4096, N=3072, Ktot=768)
    k_gemm_bt<1><<<dim3(192), dim3(512), 0, stream>>>(xx, wckb, (void*)kcm, 3072, 768, 12, 1);

    // 6) out += k_cm @ Wcv^T  (M=4096, N=768, Ktot=3072), split-K=4, fp32 atomics
    k_gemm_bt<3><<<dim3(192), dim3(512), 0, stream>>>(kcm, wcvb, (void*)out, 768, 3072, 3, 4);
}